// Round 8
// baseline (210.217 us; speedup 1.0000x reference)
//
#include <hip/hip_runtime.h>
#include <math.h>

#define N 512
#define C 157
#define M 20

__device__ __forceinline__ float sigmoidf_(float x) {
    return 1.0f / (1.0f + __expf(-x));
}

// ws layout (floats)
#define WS_MSG  0                   // [N*C]
#define WS_FMSG (N * C)             // [N*C]
#define WS_CP   (2 * N * C)         // [N*4*C] colsum partials per quarter
#define WS_RS   (6 * N * C)         // [N*C]   rowsums
#define WS_LP   (7 * N * C)         // [N]     loss partials

// K1: msg/fmsg per n
__global__ __launch_bounds__(256) void atf_msg_kernel(
    const float* __restrict__ bank_values,
    const int* __restrict__ bank_times,
    const int* __restrict__ bank_mask,
    const int* __restrict__ ids,
    const int* __restrict__ times,
    float* __restrict__ ws)
{
    const int n   = blockIdx.x;
    const int tid = threadIdx.x;

    __shared__ float s_ts[M];
    __shared__ int   s_mk[M];

    const int   id = ids[n];
    const float t0 = (float)times[n];

    if (tid < M) {
        s_ts[tid] = (float)bank_times[(size_t)id * M + tid];
        s_mk[tid] = (bank_mask[(size_t)id * M + tid] != 0) ? 1 : 0;
    }
    __syncthreads();

    if (tid < C) {
        const float inv2s2 = 1.0f / (2.0f * 300.0f * 300.0f);
        const float INVDEC = 1.0f / 0.9f;
        float accP = 0.f, accF = 0.f, denP = 0.f, denF = 0.f;
        float wP = 1.f, wF = 1.f;
        const float* vb = bank_values + (size_t)id * M * C + tid;
        #pragma unroll
        for (int m = 0; m < M; ++m) {
            const float ts = s_ts[m];
            const float d  = ts - t0;
            const float kern = __expf(-d * d * inv2s2);
            const float v = vb[m * C];
            const bool mk = (s_mk[m] != 0);
            if (mk && ts < t0) { accP += wP * kern * v; denP += wP; wP *= INVDEC; }
            if (mk && ts > t0) { accF += wF * kern * v; denF += wF; wF *= INVDEC; }
        }
        ws[WS_MSG  + (size_t)n * C + tid] = (denP > 0.f) ? accP / fmaxf(denP, 1e-7f) : 0.0f;
        ws[WS_FMSG + (size_t)n * C + tid] = (denF > 0.f) ? accF / fmaxf(denF, 1e-7f) : 0.0f;
    }
}

// K2: einsums over (n, quarter). grid = N*4, 256 threads (4 waves).
__global__ __launch_bounds__(256) void atf_einsum_kernel(
    const float* __restrict__ aa,
    float* __restrict__ ws)
{
    const int n   = blockIdx.x >> 2;
    const int q   = blockIdx.x & 3;
    static const int B[5] = {0, 39, 78, 117, 157};
    const int r0 = B[q], r1 = B[q + 1];

    const int tid  = threadIdx.x;
    const int wave = tid >> 6;
    const int lane = tid & 63;

    __shared__ float s_msg[C];
    __shared__ float s_colp[4][C];

    // stage msg into LDS (broadcast use), fmsg into registers (per-lane use)
    if (tid < C) s_msg[tid] = ws[WS_MSG + (size_t)n * C + tid];

    const int j0 = lane, j1 = lane + 64, j2 = lane + 128;
    const bool ok1 = (j1 < C), ok2 = (j2 < C);
    const float* fm = ws + WS_FMSG + (size_t)n * C;
    const float f0 = fm[j0];
    const float f1 = ok1 ? fm[j1] : 0.0f;
    const float f2 = ok2 ? fm[j2] : 0.0f;
    __syncthreads();

    const float* aan = aa + (size_t)n * C * C;
    float* rs = ws + WS_RS + (size_t)n * C;

    float c0 = 0.f, c1 = 0.f, c2 = 0.f;
    for (int i = r0 + wave; i < r1; i += 4) {
        const float* row = aan + i * C;
        const float v0 = row[j0];
        const float v1 = ok1 ? row[j1] : 0.0f;
        const float v2 = ok2 ? row[j2] : 0.0f;
        const float mi = s_msg[i];
        c0 += v0 * mi;
        c1 += v1 * mi;
        c2 += v2 * mi;
        float rp = v0 * f0 + v1 * f1 + v2 * f2;
        #pragma unroll
        for (int off = 32; off > 0; off >>= 1) rp += __shfl_down(rp, off, 64);
        if (lane == 0) rs[i] = rp;
    }
    s_colp[wave][j0] = c0;
    if (ok1) s_colp[wave][j1] = c1;
    if (ok2) s_colp[wave][j2] = c2;
    __syncthreads();

    if (tid < C) {
        ws[WS_CP + ((size_t)(4 * n + q)) * C + tid] =
            s_colp[0][tid] + s_colp[1][tid] + s_colp[2][tid] + s_colp[3][tid];
    }
}

// K3: epilogue per n
__global__ __launch_bounds__(256) void atf_epilogue_kernel(
    const float* __restrict__ a,
    const float* __restrict__ target,
    float* __restrict__ ws,
    float* __restrict__ out)
{
    const int n    = blockIdx.x;
    const int tid  = threadIdx.x;
    const int wave = tid >> 6;
    const int lane = tid & 63;
    __shared__ float s_red[4];

    float local = 0.0f;
    if (tid < C) {
        const float colsum = ws[WS_CP + ((size_t)(4 * n + 0)) * C + tid]
                           + ws[WS_CP + ((size_t)(4 * n + 1)) * C + tid]
                           + ws[WS_CP + ((size_t)(4 * n + 2)) * C + tid]
                           + ws[WS_CP + ((size_t)(4 * n + 3)) * C + tid];
        const float rowsum = ws[WS_RS + (size_t)n * C + tid];
        const float av = a[(size_t)n * C + tid];
        const float qlin = av + colsum + rowsum;
        const float p = sigmoidf_(qlin);
        out[(size_t)n * C + tid] = p;

        const float t = target[(size_t)n * C + tid];
        float pc = fminf(fmaxf(p, 1e-7f), 1.0f - 1e-7f);
        float pa = sigmoidf_(av);
        pa = fminf(fmaxf(pa, 1e-7f), 1.0f - 1e-7f);
        local = t * logf(pc) + (1.0f - t) * logf(1.0f - pc)
              + t * logf(pa) + (1.0f - t) * logf(1.0f - pa);
    }
    #pragma unroll
    for (int off = 32; off > 0; off >>= 1) local += __shfl_down(local, off, 64);
    if (lane == 0) s_red[wave] = local;
    __syncthreads();
    if (tid == 0) {
        ws[WS_LP + n] = s_red[0] + s_red[1] + s_red[2] + s_red[3];
    }
}

// K4: finalize
__global__ __launch_bounds__(256) void atf_finalize_kernel(
    const float* __restrict__ loss_part,
    float* __restrict__ out)
{
    const int tid  = threadIdx.x;
    const int wave = tid >> 6;
    const int lane = tid & 63;
    __shared__ double s_red[4];

    double local = (double)loss_part[tid] + (double)loss_part[tid + 256];
    #pragma unroll
    for (int off = 32; off > 0; off >>= 1) local += __shfl_down(local, off, 64);
    if (lane == 0) s_red[wave] = local;
    __syncthreads();
    if (tid == 0) {
        const double s = s_red[0] + s_red[1] + s_red[2] + s_red[3];
        out[N * C] = (float)(-s / ((double)(N * C) * 3.0));
    }
}

extern "C" void kernel_launch(void* const* d_in, const int* in_sizes, int n_in,
                              void* d_out, int out_size, void* d_ws, size_t ws_size,
                              hipStream_t stream) {
    const float* a           = (const float*)d_in[0];
    const float* aa          = (const float*)d_in[1];
    const float* target      = (const float*)d_in[2];
    const float* bank_values = (const float*)d_in[3];
    const int*   bank_times  = (const int*)d_in[4];
    const int*   bank_mask   = (const int*)d_in[5];
    const int*   ids         = (const int*)d_in[6];
    const int*   times       = (const int*)d_in[7];

    float* out = (float*)d_out;
    float* ws  = (float*)d_ws;

    atf_msg_kernel<<<N, 256, 0, stream>>>(bank_values, bank_times, bank_mask,
                                          ids, times, ws);
    atf_einsum_kernel<<<N * 4, 256, 0, stream>>>(aa, ws);
    atf_epilogue_kernel<<<N, 256, 0, stream>>>(a, target, ws, out);
    atf_finalize_kernel<<<1, 256, 0, stream>>>(ws + WS_LP, out);
}